// Round 2
// baseline (488.625 us; speedup 1.0000x reference)
//
#include <hip/hip_runtime.h>
#include <stdint.h>

typedef unsigned short u16;
typedef unsigned int u32;

typedef __bf16 bf16x8 __attribute__((ext_vector_type(8)));
typedef float f32x4 __attribute__((ext_vector_type(4)));

#define NQ 6291456   // B*S*AD = 16*512*768
#define NW 589824    // 768*768
#define INV_SCALE 0.03608439182435161f  // 1/sqrt(768)

__device__ __forceinline__ u16 f2bf(float f) {
    u32 u = __float_as_uint(f);
    u32 r = (u + 0x7fffu + ((u >> 16) & 1u)) >> 16;
    return (u16)r;
}

// async global->LDS, 16B per lane; LDS dest must be the wave-uniform chunk base
__device__ __forceinline__ void gload_lds16(const void* g, void* l) {
    __builtin_amdgcn_global_load_lds(
        (const __attribute__((address_space(1))) char*)(uintptr_t)g,
        (__attribute__((address_space(3))) char*)(uintptr_t)l, 16, 0, 0);
}

__device__ __forceinline__ f32x4 mfma16(bf16x8 a, bf16x8 b, f32x4 c) {
    return __builtin_amdgcn_mfma_f32_16x16x32_bf16(a, b, c, 0, 0, 0);
}

// ---------------------------------------------------------------------------
// fp32 -> bf16 conversion, float4 in / ushort4 out
// ---------------------------------------------------------------------------
__global__ __launch_bounds__(256) void cvt(const float* __restrict__ s,
                                           u16* __restrict__ d, int n4)
{
    int i = blockIdx.x * 256 + threadIdx.x;
    if (i < n4) {
        float4 v = ((const float4*)s)[i];
        ushort4 o;
        o.x = f2bf(v.x); o.y = f2bf(v.y); o.z = f2bf(v.z); o.w = f2bf(v.w);
        ((ushort4*)d)[i] = o;
    }
}

// ---------------------------------------------------------------------------
// Fused q/k/v projection GEMM: C[M,N] = A[M,K] @ W[N,K]^T + bias
// M=8192, N=768, K=768.  grid=(64,6,3): z selects (q|k|v).
// 128x128 tile, BK=64, 4 waves each computing 64x64 (4x4 16x16 frags).
// LDS tiles [128 rows][64 k] bf16, XOR-swizzled 16B slots: slot' = slot ^ (row&7)
// ---------------------------------------------------------------------------
__global__ __launch_bounds__(256, 2) void proj_gemm(
    const u16* __restrict__ A0, const u16* __restrict__ A1,
    const u16* __restrict__ Wq, const u16* __restrict__ Wk, const u16* __restrict__ Wv,
    const float* __restrict__ bq, const float* __restrict__ bk, const float* __restrict__ bv,
    u16* __restrict__ oq, u16* __restrict__ ok, u16* __restrict__ ov)
{
    __shared__ u16 sA[8192];  // 128*64
    __shared__ u16 sB[8192];

    const int z = blockIdx.z;
    const u16* A       = (z == 0) ? A0 : A1;
    const u16* W       = (z == 0) ? Wq : ((z == 1) ? Wk : Wv);
    const float* bias  = (z == 0) ? bq : ((z == 1) ? bk : bv);
    u16* out           = (z == 0) ? oq : ((z == 1) ? ok : ov);

    const int tid = threadIdx.x;
    const int wave = tid >> 6, lane = tid & 63;
    const int m0 = blockIdx.x * 128, n0 = blockIdx.y * 128;
    const int wrow = wave >> 1, wcol = wave & 1;
    const int lr = lane & 15, lg = lane >> 4;

    f32x4 acc[4][4];
#pragma unroll
    for (int mi = 0; mi < 4; ++mi)
#pragma unroll
        for (int ni = 0; ni < 4; ++ni)
            acc[mi][ni] = (f32x4){0.f, 0.f, 0.f, 0.f};

    for (int ks = 0; ks < 12; ++ks) {
        const int k0 = ks * 64;
#pragma unroll
        for (int i = 0; i < 4; ++i) {
            const int Lb = wave * 4096 + i * 1024;      // wave-uniform LDS byte base
            const int L = Lb + lane * 16;
            const int row = L >> 7;                     // 0..127
            const int sc16 = (lane & 7) ^ (row & 7);    // pre-swizzled source slot
            gload_lds16(A + (size_t)(m0 + row) * 768 + k0 + sc16 * 8, (char*)sA + Lb);
            gload_lds16(W + (size_t)(n0 + row) * 768 + k0 + sc16 * 8, (char*)sB + Lb);
        }
        __syncthreads();
#pragma unroll
        for (int kk = 0; kk < 2; ++kk) {
            bf16x8 af[4], bfr[4];
#pragma unroll
            for (int t = 0; t < 4; ++t) {
                const int ar = wrow * 64 + t * 16 + lr;
                const int ac = (kk * 4 + lg) ^ (ar & 7);
                af[t] = *(const bf16x8*)((const char*)sA + ar * 128 + ac * 16);
                const int br = wcol * 64 + t * 16 + lr;
                const int bc = (kk * 4 + lg) ^ (br & 7);
                bfr[t] = *(const bf16x8*)((const char*)sB + br * 128 + bc * 16);
            }
#pragma unroll
            for (int mi = 0; mi < 4; ++mi)
#pragma unroll
                for (int ni = 0; ni < 4; ++ni)
                    acc[mi][ni] = mfma16(af[mi], bfr[ni], acc[mi][ni]);
        }
        __syncthreads();
    }

    float bvv[4] = {0.f, 0.f, 0.f, 0.f};
    if (bias) {
#pragma unroll
        for (int ni = 0; ni < 4; ++ni)
            bvv[ni] = bias[n0 + wcol * 64 + ni * 16 + lr];
    }
#pragma unroll
    for (int mi = 0; mi < 4; ++mi) {
#pragma unroll
        for (int ni = 0; ni < 4; ++ni) {
#pragma unroll
            for (int r = 0; r < 4; ++r) {
                const int rowM = m0 + wrow * 64 + mi * 16 + lg * 4 + r;
                const int colN = n0 + wcol * 64 + ni * 16 + lr;
                out[(size_t)rowM * 768 + colN] = f2bf(acc[mi][ni][r] + bvv[ni]);
            }
        }
    }
}

// ---------------------------------------------------------------------------
// V transpose: v[b][s][h*64+d] -> vT[b][h][d][s]   (64x64 tiles via LDS)
// grid = B*H*8 = 1536 blocks, 256 threads
// ---------------------------------------------------------------------------
__global__ __launch_bounds__(256) void vtrans(const u16* __restrict__ v, u16* __restrict__ vT)
{
    __shared__ u16 t[64][80];
    const int blk = blockIdx.x;
    const int b = blk / 96, h = (blk / 8) % 12, st = blk & 7;
    const int tid = threadIdx.x;

    const u16* src = v + (size_t)(b * 512 + st * 64) * 768 + h * 64;
#pragma unroll
    for (int p = 0; p < 2; ++p) {
        const int srow = p * 32 + (tid >> 3), dp = tid & 7;
        uint4 d = *(const uint4*)(src + (size_t)srow * 768 + dp * 8);
        *(uint4*)&t[srow][dp * 8] = d;
    }
    __syncthreads();
    u16* dst = vT + (size_t)((b * 12 + h) * 64) * 512 + st * 64;
#pragma unroll
    for (int p = 0; p < 2; ++p) {
        const int drow = p * 32 + (tid >> 3), sp = tid & 7;
        union { u16 u[8]; uint4 v4; } o;
#pragma unroll
        for (int j = 0; j < 8; ++j) o.u[j] = t[sp * 8 + j][drow];
        *(uint4*)(dst + (size_t)drow * 512 + sp * 8) = o.v4;
    }
}

// ---------------------------------------------------------------------------
// Fused attention for one (b,h,qchunk): 4 waves x 16 q-rows, full 512 keys.
// softmax(tanh(QK^T)/sqrt(768)) with no max-subtraction (logits bounded).
// P~ (unnormalized exp) kept in per-wave swizzled LDS; normalization folded
// into PV epilogue.  FINAL: write fp32 ctx twice + fp32 normalized scores.
// ---------------------------------------------------------------------------
template <bool FINAL>
__global__ __launch_bounds__(256, 2) void attn_kernel(
    const u16* __restrict__ q, const u16* __restrict__ k, const u16* __restrict__ vT,
    u16* __restrict__ ctxb, float* __restrict__ ctxf, float* __restrict__ sc)
{
    __shared__ u16 sP[4][8192];   // per wave: 16 rows x 512 keys, XOR-swizzled
    __shared__ float ssum[4][16];

    const int blk = blockIdx.x;
    const int b = blk / 96, h = (blk / 8) % 12, qc = blk & 7;
    const int tid = threadIdx.x, wave = tid >> 6, lane = tid & 63;
    const int q0 = qc * 64 + wave * 16;
    const int lr = lane & 15, lg = lane >> 4;
    char* myP = (char*)sP[wave];

    // Q fragments (hoisted: same for all key tiles)
    const u16* qbase = q + (size_t)(b * 512 + q0 + lr) * 768 + h * 64 + lg * 8;
    bf16x8 aq0 = *(const bf16x8*)(qbase);
    bf16x8 aq1 = *(const bf16x8*)(qbase + 32);

    float psum[4] = {0.f, 0.f, 0.f, 0.f};
    const u16* kbase = k + (size_t)(b * 512 + lr) * 768 + h * 64 + lg * 8;

    for (int kt = 0; kt < 32; ++kt) {
        f32x4 s4 = (f32x4){0.f, 0.f, 0.f, 0.f};
        const u16* kb = kbase + (size_t)kt * 16 * 768;
        s4 = mfma16(aq0, *(const bf16x8*)kb, s4);
        s4 = mfma16(aq1, *(const bf16x8*)(kb + 32), s4);
#pragma unroll
        for (int r = 0; r < 4; ++r) {
            const int row = lg * 4 + r;
            float e = __expf(2.f * s4[r]);
            float th = 1.f - __fdividef(2.f, e + 1.f);   // tanh(s)
            float p = __expf(th * INV_SCALE);
            psum[r] += p;
            const int byte = (row * 1024 + (kt * 16 + lr) * 2) ^ ((row & 7) << 4);
            *(u16*)(myP + byte) = f2bf(p);
        }
    }
#pragma unroll
    for (int r = 0; r < 4; ++r) {
        psum[r] += __shfl_xor(psum[r], 1);
        psum[r] += __shfl_xor(psum[r], 2);
        psum[r] += __shfl_xor(psum[r], 4);
        psum[r] += __shfl_xor(psum[r], 8);
    }
    float inv[4];
#pragma unroll
    for (int r = 0; r < 4; ++r) inv[r] = 1.f / psum[r];

    if (FINAL && lr == 0) {
#pragma unroll
        for (int r = 0; r < 4; ++r) ssum[wave][lg * 4 + r] = inv[r];
    }

    // PV: ctx[q][d] = sum_key P~ * V, scaled by inv at the end
    const u16* vb0 = vT + (size_t)((b * 12 + h) * 64 + lr) * 512 + lg * 8;
#pragma unroll
    for (int dt = 0; dt < 4; ++dt) {
        f32x4 o = (f32x4){0.f, 0.f, 0.f, 0.f};
        const u16* vbb = vb0 + (size_t)dt * 16 * 512;
#pragma unroll
        for (int pk = 0; pk < 16; ++pk) {
            const int byte = (lr * 1024 + pk * 64 + lg * 16) ^ ((lr & 7) << 4);
            bf16x8 pa = *(const bf16x8*)(myP + byte);
            bf16x8 vb = *(const bf16x8*)(vbb + pk * 32);
            o = mfma16(pa, vb, o);
        }
#pragma unroll
        for (int r = 0; r < 4; ++r) {
            const int rowq = lg * 4 + r;
            const float val = o[r] * inv[r];
            const size_t gi = (size_t)(b * 512 + q0 + rowq) * 768 + h * 64 + dt * 16 + lr;
            if (FINAL) {
                ctxf[gi] = val;
                ctxf[gi + (size_t)NQ] = val;
            } else {
                ctxb[gi] = f2bf(val);
            }
        }
    }

    if (FINAL) {
#pragma unroll
        for (int row = 0; row < 16; ++row) {
            const float is = ssum[wave][row];
            const int byte = (row * 1024 + lane * 16) ^ ((row & 7) << 4);
            bf16x8 pv8 = *(const bf16x8*)(myP + byte);
            float4 o0, o1;
            o0.x = (float)pv8[0] * is; o0.y = (float)pv8[1] * is;
            o0.z = (float)pv8[2] * is; o0.w = (float)pv8[3] * is;
            o1.x = (float)pv8[4] * is; o1.y = (float)pv8[5] * is;
            o1.z = (float)pv8[6] * is; o1.w = (float)pv8[7] * is;
            float* dstp = sc + ((size_t)((h * 16 + b) * 512 + q0 + row)) * 512 + lane * 8;
            *(float4*)dstp = o0;
            *(float4*)(dstp + 4) = o1;
        }
    }
}

// ---------------------------------------------------------------------------
extern "C" void kernel_launch(void* const* d_in, const int* in_sizes, int n_in,
                              void* d_out, int out_size, void* d_ws, size_t ws_size,
                              hipStream_t stream)
{
    if (n_in < 11) return;
    const float* seq1 = (const float*)d_in[0];
    const float* seq2 = (const float*)d_in[1];
    const float* Wq  = (const float*)d_in[2];
    const float* Wk  = (const float*)d_in[3];
    const float* Wv  = (const float*)d_in[4];
    const float* Wq1 = (const float*)d_in[5];
    const float* bq1 = (const float*)d_in[6];
    const float* Wk1 = (const float*)d_in[7];
    const float* bk1 = (const float*)d_in[8];
    const float* Wv1 = (const float*)d_in[9];
    const float* bv1 = (const float*)d_in[10];

    // ws layout (u16 elements): 7*NQ + 9*NW  = ~98.7 MB
    if (ws_size < ((size_t)7 * NQ + 9 * NW) * 2) return;
    u16* ws   = (u16*)d_ws;
    u16* q    = ws;
    u16* kk   = ws + (size_t)NQ;
    u16* vv   = ws + (size_t)2 * NQ;
    u16* vT   = ws + (size_t)3 * NQ;
    u16* ctx  = ws + (size_t)4 * NQ;
    u16* bs1  = ws + (size_t)5 * NQ;
    u16* bs2  = ws + (size_t)6 * NQ;
    u16* bWq  = ws + (size_t)7 * NQ;
    u16* bWk  = bWq  + (size_t)NW;
    u16* bWv  = bWk  + (size_t)NW;
    u16* bWq1 = bWv  + (size_t)NW;       // 2 layers
    u16* bWk1 = bWq1 + (size_t)2 * NW;
    u16* bWv1 = bWk1 + (size_t)2 * NW;

    float* out = (float*)d_out;

    // fp32 -> bf16 conversions
    cvt<<<6144, 256, 0, stream>>>(seq1, bs1, NQ / 4);
    cvt<<<6144, 256, 0, stream>>>(seq2, bs2, NQ / 4);
    cvt<<<576, 256, 0, stream>>>(Wq, bWq, NW / 4);
    cvt<<<576, 256, 0, stream>>>(Wk, bWk, NW / 4);
    cvt<<<576, 256, 0, stream>>>(Wv, bWv, NW / 4);
    cvt<<<1152, 256, 0, stream>>>(Wq1, bWq1, NW / 2);
    cvt<<<1152, 256, 0, stream>>>(Wk1, bWk1, NW / 2);
    cvt<<<1152, 256, 0, stream>>>(Wv1, bWv1, NW / 2);

    dim3 pgrid(64, 6, 3);

    // layer 1 (no bias)
    proj_gemm<<<pgrid, 256, 0, stream>>>(bs1, bs2, bWq, bWk, bWv,
                                         nullptr, nullptr, nullptr, q, kk, vv);
    vtrans<<<1536, 256, 0, stream>>>(vv, vT);
    attn_kernel<false><<<1536, 256, 0, stream>>>(q, kk, vT, ctx, nullptr, nullptr);

    // layer 2
    proj_gemm<<<pgrid, 256, 0, stream>>>(ctx, ctx, bWq1, bWk1, bWv1,
                                         bq1, bk1, bv1, q, kk, vv);
    vtrans<<<1536, 256, 0, stream>>>(vv, vT);
    attn_kernel<false><<<1536, 256, 0, stream>>>(q, kk, vT, ctx, nullptr, nullptr);

    // layer 3 (writes fp32 ctx twice + fp32 normalized scores to d_out)
    proj_gemm<<<pgrid, 256, 0, stream>>>(ctx, ctx, bWq1 + (size_t)NW, bWk1 + (size_t)NW,
                                         bWv1 + (size_t)NW,
                                         bq1 + 768, bk1 + 768, bv1 + 768, q, kk, vv);
    vtrans<<<1536, 256, 0, stream>>>(vv, vT);
    attn_kernel<true><<<1536, 256, 0, stream>>>(q, kk, vT, nullptr, out,
                                                out + (size_t)2 * NQ);
}

// Round 3
// 452.610 us; speedup vs baseline: 1.0796x; 1.0796x over previous
//
#include <hip/hip_runtime.h>
#include <stdint.h>

typedef unsigned short u16;
typedef unsigned int u32;

typedef __bf16 bf16x8 __attribute__((ext_vector_type(8)));
typedef float f32x4 __attribute__((ext_vector_type(4)));

#define NQ 6291456   // B*S*AD = 16*512*768
#define NW 589824    // 768*768
#define INV_SCALE 0.03608439182435161f  // 1/sqrt(768)
#define LOG2E2 2.885390081777927f       // 2*log2(e)

__device__ __forceinline__ u16 f2bf(float f) {
    u32 u = __float_as_uint(f);
    u32 r = (u + 0x7fffu + ((u >> 16) & 1u)) >> 16;
    return (u16)r;
}

// p = exp(tanh(s) * INV_SCALE); tanh via 1 exp2 + rcp, outer exp via 3-term
// poly (|arg| <= 0.0361 -> rel err ~7e-8, far below bf16 storage rounding)
__device__ __forceinline__ float score_p(float s) {
    float e  = exp2f(LOG2E2 * s);
    float th = 1.f - __fdividef(2.f, e + 1.f);
    float a  = th * INV_SCALE;
    return fmaf(a, fmaf(a, fmaf(a, 0.16666667f, 0.5f), 1.f), 1.f);
}

// async global->LDS, 16B per lane; LDS dest must be the wave-uniform chunk base
__device__ __forceinline__ void gload_lds16(const void* g, void* l) {
    __builtin_amdgcn_global_load_lds(
        (const __attribute__((address_space(1))) char*)(uintptr_t)g,
        (__attribute__((address_space(3))) char*)(uintptr_t)l, 16, 0, 0);
}

__device__ __forceinline__ f32x4 mfma16(bf16x8 a, bf16x8 b, f32x4 c) {
    return __builtin_amdgcn_mfma_f32_16x16x32_bf16(a, b, c, 0, 0, 0);
}

#define LDS_FENCE() asm volatile("s_waitcnt lgkmcnt(0)" ::: "memory")

// ---------------------------------------------------------------------------
// fp32 -> bf16 conversion for all 8 tensors in ONE launch. Linear grid with
// per-block segment lookup from a small table (8 segments).
// ---------------------------------------------------------------------------
struct CvtArgs {
    const float* src[8];
    u16* dst[8];
    int blk_start[8];   // first block of each segment
    int n4[8];          // float4 count per segment
};

__global__ __launch_bounds__(256) void cvt_multi(CvtArgs a)
{
    const int bid = blockIdx.x;
    int seg = 0;
#pragma unroll
    for (int s = 1; s < 8; ++s) seg += (bid >= a.blk_start[s]);
    const int i = (bid - a.blk_start[seg]) * 256 + threadIdx.x;
    if (i < a.n4[seg]) {
        float4 v = ((const float4*)a.src[seg])[i];
        ushort4 o;
        o.x = f2bf(v.x); o.y = f2bf(v.y); o.z = f2bf(v.z); o.w = f2bf(v.w);
        ((ushort4*)a.dst[seg])[i] = o;
    }
}

// ---------------------------------------------------------------------------
// Fused q/k/v projection GEMM: C[M,N] = A[M,K] @ W[N,K]^T + bias
// M=8192, N=768, K=768.  grid=(64,6,3): z selects (q|k|v).
// 128x128 tile, BK=64, 4 waves each computing 64x64 (4x4 16x16 frags).
// Double-buffered LDS (T3 minimum 2-phase): stage(t+1) issued BEFORE
// compute(t); one vmcnt(0)+barrier per K-step (__syncthreads drains both).
// LDS tiles [128 rows][64 k] bf16, XOR-swizzled 16B slots: slot' = slot^(row&7)
// ---------------------------------------------------------------------------
__global__ __launch_bounds__(256, 2) void proj_gemm(
    const u16* __restrict__ A0, const u16* __restrict__ A1,
    const u16* __restrict__ Wq, const u16* __restrict__ Wk, const u16* __restrict__ Wv,
    const float* __restrict__ bq, const float* __restrict__ bk, const float* __restrict__ bv,
    u16* __restrict__ oq, u16* __restrict__ ok, u16* __restrict__ ov)
{
    __shared__ u16 sA[2][8192];  // 2 x 16KB
    __shared__ u16 sB[2][8192];

    const int z = blockIdx.z;
    const u16* A       = (z == 0) ? A0 : A1;
    const u16* W       = (z == 0) ? Wq : ((z == 1) ? Wk : Wv);
    const float* bias  = (z == 0) ? bq : ((z == 1) ? bk : bv);
    u16* out           = (z == 0) ? oq : ((z == 1) ? ok : ov);

    const int tid = threadIdx.x;
    const int wave = tid >> 6, lane = tid & 63;
    const int m0 = blockIdx.x * 128, n0 = blockIdx.y * 128;
    const int wrow = wave >> 1, wcol = wave & 1;
    const int lr = lane & 15, lg = lane >> 4;

    // per-thread staging addresses (row/slot fixed across K-steps)
    const int Lb0 = wave * 4096;                 // byte base of wave's chunk 0
    const int srow = (Lb0 + lane * 16) >> 7;     // uses chunk i -> row += 8i
    const int ssl = (lane & 7);

    f32x4 acc[4][4];
#pragma unroll
    for (int mi = 0; mi < 4; ++mi)
#pragma unroll
        for (int ni = 0; ni < 4; ++ni)
            acc[mi][ni] = (f32x4){0.f, 0.f, 0.f, 0.f};

#define STAGE(buf, k0)                                                          \
    {                                                                           \
        _Pragma("unroll")                                                       \
        for (int i = 0; i < 4; ++i) {                                           \
            const int row = srow + i * 8;                                       \
            const int sc16 = ssl ^ (row & 7);                                   \
            gload_lds16(A + (size_t)(m0 + row) * 768 + (k0) + sc16 * 8,         \
                        (char*)sA[buf] + Lb0 + i * 1024);                       \
            gload_lds16(W + (size_t)(n0 + row) * 768 + (k0) + sc16 * 8,         \
                        (char*)sB[buf] + Lb0 + i * 1024);                       \
        }                                                                       \
    }

    STAGE(0, 0);
    __syncthreads();

    for (int ks = 0; ks < 12; ++ks) {
        const int cur = ks & 1;
        if (ks < 11) STAGE(cur ^ 1, (ks + 1) * 64);
#pragma unroll
        for (int kk = 0; kk < 2; ++kk) {
            bf16x8 af[4], bfr[4];
#pragma unroll
            for (int t = 0; t < 4; ++t) {
                const int ar = wrow * 64 + t * 16 + lr;
                const int ac = (kk * 4 + lg) ^ (ar & 7);
                af[t] = *(const bf16x8*)((const char*)sA[cur] + ar * 128 + ac * 16);
                const int br = wcol * 64 + t * 16 + lr;
                const int bc = (kk * 4 + lg) ^ (br & 7);
                bfr[t] = *(const bf16x8*)((const char*)sB[cur] + br * 128 + bc * 16);
            }
#pragma unroll
            for (int mi = 0; mi < 4; ++mi)
#pragma unroll
                for (int ni = 0; ni < 4; ++ni)
                    acc[mi][ni] = mfma16(af[mi], bfr[ni], acc[mi][ni]);
        }
        __syncthreads();   // waits vmcnt(0) (next tile staged) + lgkmcnt
    }
#undef STAGE

    float bvv[4] = {0.f, 0.f, 0.f, 0.f};
    if (bias) {
#pragma unroll
        for (int ni = 0; ni < 4; ++ni)
            bvv[ni] = bias[n0 + wcol * 64 + ni * 16 + lr];
    }
#pragma unroll
    for (int mi = 0; mi < 4; ++mi) {
#pragma unroll
        for (int ni = 0; ni < 4; ++ni) {
#pragma unroll
            for (int r = 0; r < 4; ++r) {
                const int rowM = m0 + wrow * 64 + mi * 16 + lg * 4 + r;
                const int colN = n0 + wcol * 64 + ni * 16 + lr;
                out[(size_t)rowM * 768 + colN] = f2bf(acc[mi][ni][r] + bvv[ni]);
            }
        }
    }
}

// ---------------------------------------------------------------------------
// V transpose: v[b][s][h*64+d] -> vT[b][h][d][s]   (64x64 tiles via LDS)
// ---------------------------------------------------------------------------
__global__ __launch_bounds__(256) void vtrans(const u16* __restrict__ v, u16* __restrict__ vT)
{
    __shared__ u16 t[64][80];
    const int blk = blockIdx.x;
    const int b = blk / 96, h = (blk / 8) % 12, st = blk & 7;
    const int tid = threadIdx.x;

    const u16* src = v + (size_t)(b * 512 + st * 64) * 768 + h * 64;
#pragma unroll
    for (int p = 0; p < 2; ++p) {
        const int srow = p * 32 + (tid >> 3), dp = tid & 7;
        uint4 d = *(const uint4*)(src + (size_t)srow * 768 + dp * 8);
        *(uint4*)&t[srow][dp * 8] = d;
    }
    __syncthreads();
    u16* dst = vT + (size_t)((b * 12 + h) * 64) * 512 + st * 64;
#pragma unroll
    for (int p = 0; p < 2; ++p) {
        const int drow = p * 32 + (tid >> 3), sp = tid & 7;
        union { u16 u[8]; uint4 v4; } o;
#pragma unroll
        for (int j = 0; j < 8; ++j) o.u[j] = t[sp * 8 + j][drow];
        *(uint4*)(dst + (size_t)drow * 512 + sp * 8) = o.v4;
    }
}

// ---------------------------------------------------------------------------
// Streaming attention (layers 1,2): per 32-key window compute QK^T, p-vals,
// bounce the 16x32 P~ tile through a tiny swizzled LDS buffer (1.25KB/wave,
// double-buffered), and immediately accumulate PV. No persistent P -> LDS
// down from 64KB to 10KB/block -> 4 blocks/CU.
// ---------------------------------------------------------------------------
__global__ __launch_bounds__(256, 4) void attn_stream(
    const u16* __restrict__ q, const u16* __restrict__ k, const u16* __restrict__ vT,
    u16* __restrict__ ctx)
{
    __shared__ u16 sS[4][2][640];   // per wave, 2 bufs: 16 rows x 80B stride

    const int blk = blockIdx.x;
    const int b = blk / 96, h = (blk / 8) % 12, qc = blk & 7;
    const int tid = threadIdx.x, wave = tid >> 6, lane = tid & 63;
    const int q0 = qc * 64 + wave * 16;
    const int lr = lane & 15, lg = lane >> 4;

    const u16* qbase = q + (size_t)(b * 512 + q0 + lr) * 768 + h * 64 + lg * 8;
    bf16x8 aq0 = *(const bf16x8*)(qbase);
    bf16x8 aq1 = *(const bf16x8*)(qbase + 32);

    const u16* kbase = k + (size_t)(b * 512 + lr) * 768 + h * 64 + lg * 8;
    const u16* vbase = vT + (size_t)((b * 12 + h) * 64 + lr) * 512 + lg * 8;

    // LDS bounce addresses (bytes). write: row q=lg*4+r, key c*16+lr
    // map(q,key) = q*80 + ((key*2) ^ ((q&3)<<4)); read 16B chunk keys lg*8..
    char* const myS0 = (char*)sS[wave][0];
    const int rdoff = lr * 80 + ((lg * 16) ^ ((lr & 3) << 4));

    float psum[4] = {0.f, 0.f, 0.f, 0.f};
    f32x4 o[4];
#pragma unroll
    for (int dt = 0; dt < 4; ++dt) o[dt] = (f32x4){0.f, 0.f, 0.f, 0.f};

    for (int w = 0; w < 16; ++w) {
        char* myS = myS0 + (w & 1) * 1280;
        const u16* kb = kbase + (size_t)w * 32 * 768;
        f32x4 s4a = (f32x4){0.f, 0.f, 0.f, 0.f};
        f32x4 s4b = (f32x4){0.f, 0.f, 0.f, 0.f};
        s4a = mfma16(aq0, *(const bf16x8*)kb, s4a);
        s4a = mfma16(aq1, *(const bf16x8*)(kb + 32), s4a);
        const u16* kb2 = kb + 16 * 768;
        s4b = mfma16(aq0, *(const bf16x8*)kb2, s4b);
        s4b = mfma16(aq1, *(const bf16x8*)(kb2 + 32), s4b);

#pragma unroll
        for (int c = 0; c < 2; ++c) {
#pragma unroll
            for (int r = 0; r < 4; ++r) {
                const float s = c ? s4b[r] : s4a[r];
                const float p = score_p(s);
                psum[r] += p;
                const int row = lg * 4 + r;
                const int byte = row * 80 + (((c * 16 + lr) * 2) ^ ((r & 3) << 4));
                *(u16*)(myS + byte) = f2bf(p);
            }
        }
        LDS_FENCE();   // wave-local: writes visible before cross-lane read
        bf16x8 pa = *(const bf16x8*)(myS + rdoff);
#pragma unroll
        for (int dt = 0; dt < 4; ++dt) {
            bf16x8 vb = *(const bf16x8*)(vbase + (size_t)dt * 16 * 512 + w * 32);
            o[dt] = mfma16(pa, vb, o[dt]);
        }
    }

#pragma unroll
    for (int r = 0; r < 4; ++r) {
        psum[r] += __shfl_xor(psum[r], 1);
        psum[r] += __shfl_xor(psum[r], 2);
        psum[r] += __shfl_xor(psum[r], 4);
        psum[r] += __shfl_xor(psum[r], 8);
    }
    float inv[4];
#pragma unroll
    for (int r = 0; r < 4; ++r) inv[r] = 1.f / psum[r];

#pragma unroll
    for (int dt = 0; dt < 4; ++dt) {
#pragma unroll
        for (int r = 0; r < 4; ++r) {
            const size_t gi = (size_t)(b * 512 + q0 + lg * 4 + r) * 768 + h * 64 + dt * 16 + lr;
            ctx[gi] = f2bf(o[dt][r] * inv[r]);
        }
    }
}

// ---------------------------------------------------------------------------
// Final-layer attention: persistent P~ in big swizzled LDS (needed for the
// full normalized-score output), fp32 ctx written twice + fp32 scores.
// ---------------------------------------------------------------------------
__global__ __launch_bounds__(256, 2) void attn_final(
    const u16* __restrict__ q, const u16* __restrict__ k, const u16* __restrict__ vT,
    float* __restrict__ ctxf, float* __restrict__ sc)
{
    __shared__ u16 sP[4][8192];   // per wave: 16 rows x 512 keys, XOR-swizzled
    __shared__ float ssum[4][16];

    const int blk = blockIdx.x;
    const int b = blk / 96, h = (blk / 8) % 12, qc = blk & 7;
    const int tid = threadIdx.x, wave = tid >> 6, lane = tid & 63;
    const int q0 = qc * 64 + wave * 16;
    const int lr = lane & 15, lg = lane >> 4;
    char* myP = (char*)sP[wave];

    const u16* qbase = q + (size_t)(b * 512 + q0 + lr) * 768 + h * 64 + lg * 8;
    bf16x8 aq0 = *(const bf16x8*)(qbase);
    bf16x8 aq1 = *(const bf16x8*)(qbase + 32);

    float psum[4] = {0.f, 0.f, 0.f, 0.f};
    const u16* kbase = k + (size_t)(b * 512 + lr) * 768 + h * 64 + lg * 8;

    for (int kt = 0; kt < 32; ++kt) {
        f32x4 s4 = (f32x4){0.f, 0.f, 0.f, 0.f};
        const u16* kb = kbase + (size_t)kt * 16 * 768;
        s4 = mfma16(aq0, *(const bf16x8*)kb, s4);
        s4 = mfma16(aq1, *(const bf16x8*)(kb + 32), s4);
#pragma unroll
        for (int r = 0; r < 4; ++r) {
            const int row = lg * 4 + r;
            const float p = score_p(s4[r]);
            psum[r] += p;
            const int byte = (row * 1024 + (kt * 16 + lr) * 2) ^ ((row & 7) << 4);
            *(u16*)(myP + byte) = f2bf(p);
        }
    }
#pragma unroll
    for (int r = 0; r < 4; ++r) {
        psum[r] += __shfl_xor(psum[r], 1);
        psum[r] += __shfl_xor(psum[r], 2);
        psum[r] += __shfl_xor(psum[r], 4);
        psum[r] += __shfl_xor(psum[r], 8);
    }
    float inv[4];
#pragma unroll
    for (int r = 0; r < 4; ++r) inv[r] = 1.f / psum[r];

    if (lr == 0) {
#pragma unroll
        for (int r = 0; r < 4; ++r) ssum[wave][lg * 4 + r] = inv[r];
    }

    const u16* vb0 = vT + (size_t)((b * 12 + h) * 64 + lr) * 512 + lg * 8;
#pragma unroll
    for (int dt = 0; dt < 4; ++dt) {
        f32x4 o = (f32x4){0.f, 0.f, 0.f, 0.f};
        const u16* vbb = vb0 + (size_t)dt * 16 * 512;
#pragma unroll
        for (int pk = 0; pk < 16; ++pk) {
            const int byte = (lr * 1024 + pk * 64 + lg * 16) ^ ((lr & 7) << 4);
            bf16x8 pa = *(const bf16x8*)(myP + byte);
            bf16x8 vb = *(const bf16x8*)(vbb + pk * 32);
            o = mfma16(pa, vb, o);
        }
#pragma unroll
        for (int r = 0; r < 4; ++r) {
            const float val = o[r] * inv[r];
            const size_t gi = (size_t)(b * 512 + q0 + lg * 4 + r) * 768 + h * 64 + dt * 16 + lr;
            ctxf[gi] = val;
            ctxf[gi + (size_t)NQ] = val;
        }
    }

#pragma unroll
    for (int row = 0; row < 16; ++row) {
        const float is = ssum[wave][row];
        const int byte = (row * 1024 + lane * 16) ^ ((row & 7) << 4);
        bf16x8 pv8 = *(const bf16x8*)(myP + byte);
        float4 o0, o1;
        o0.x = (float)pv8[0] * is; o0.y = (float)pv8[1] * is;
        o0.z = (float)pv8[2] * is; o0.w = (float)pv8[3] * is;
        o1.x = (float)pv8[4] * is; o1.y = (float)pv8[5] * is;
        o1.z = (float)pv8[6] * is; o1.w = (float)pv8[7] * is;
        float* dstp = sc + ((size_t)((h * 16 + b) * 512 + q0 + row)) * 512 + lane * 8;
        *(float4*)dstp = o0;
        *(float4*)(dstp + 4) = o1;
    }
}

// ---------------------------------------------------------------------------
extern "C" void kernel_launch(void* const* d_in, const int* in_sizes, int n_in,
                              void* d_out, int out_size, void* d_ws, size_t ws_size,
                              hipStream_t stream)
{
    if (n_in < 11) return;
    const float* seq1 = (const float*)d_in[0];
    const float* seq2 = (const float*)d_in[1];
    const float* Wq  = (const float*)d_in[2];
    const float* Wk  = (const float*)d_in[3];
    const float* Wv  = (const float*)d_in[4];
    const float* Wq1 = (const float*)d_in[5];
    const float* bq1 = (const float*)d_in[6];
    const float* Wk1 = (const float*)d_in[7];
    const float* bk1 = (const float*)d_in[8];
    const float* Wv1 = (const float*)d_in[9];
    const float* bv1 = (const float*)d_in[10];

    if (ws_size < ((size_t)7 * NQ + 9 * NW) * 2) return;
    u16* ws   = (u16*)d_ws;
    u16* q    = ws;
    u16* kk   = ws + (size_t)NQ;
    u16* vv   = ws + (size_t)2 * NQ;
    u16* vT   = ws + (size_t)3 * NQ;
    u16* ctx  = ws + (size_t)4 * NQ;
    u16* bs1  = ws + (size_t)5 * NQ;
    u16* bs2  = ws + (size_t)6 * NQ;
    u16* bWq  = ws + (size_t)7 * NQ;
    u16* bWk  = bWq  + (size_t)NW;
    u16* bWv  = bWk  + (size_t)NW;
    u16* bWq1 = bWv  + (size_t)NW;
    u16* bWk1 = bWq1 + (size_t)2 * NW;
    u16* bWv1 = bWk1 + (size_t)2 * NW;

    float* out = (float*)d_out;

    // single fused fp32->bf16 conversion launch
    CvtArgs ca;
    const float* srcs[8] = {seq1, seq2, Wq, Wk, Wv, Wq1, Wk1, Wv1};
    u16* dsts[8] = {bs1, bs2, bWq, bWk, bWv, bWq1, bWk1, bWv1};
    const int n4s[8] = {NQ/4, NQ/4, NW/4, NW/4, NW/4, NW/2, NW/2, NW/2};
    int acc_blk = 0;
    for (int s = 0; s < 8; ++s) {
        ca.src[s] = srcs[s]; ca.dst[s] = dsts[s]; ca.n4[s] = n4s[s];
        ca.blk_start[s] = acc_blk;
        acc_blk += (n4s[s] + 255) / 256;
    }
    cvt_multi<<<acc_blk, 256, 0, stream>>>(ca);

    dim3 pgrid(64, 6, 3);

    // layer 1 (no bias)
    proj_gemm<<<pgrid, 256, 0, stream>>>(bs1, bs2, bWq, bWk, bWv,
                                         nullptr, nullptr, nullptr, q, kk, vv);
    vtrans<<<1536, 256, 0, stream>>>(vv, vT);
    attn_stream<<<1536, 256, 0, stream>>>(q, kk, vT, ctx);

    // layer 2
    proj_gemm<<<pgrid, 256, 0, stream>>>(ctx, ctx, bWq1, bWk1, bWv1,
                                         bq1, bk1, bv1, q, kk, vv);
    vtrans<<<1536, 256, 0, stream>>>(vv, vT);
    attn_stream<<<1536, 256, 0, stream>>>(q, kk, vT, ctx);

    // layer 3 (fp32 ctx twice + fp32 normalized scores)
    proj_gemm<<<pgrid, 256, 0, stream>>>(ctx, ctx, bWq1 + (size_t)NW, bWk1 + (size_t)NW,
                                         bWv1 + (size_t)NW,
                                         bq1 + 768, bk1 + 768, bv1 + 768, q, kk, vv);
    vtrans<<<1536, 256, 0, stream>>>(vv, vT);
    attn_final<<<1536, 256, 0, stream>>>(q, kk, vT, out, out + (size_t)2 * NQ);
}